// Round 22
// baseline (125.344 us; speedup 1.0000x reference)
//
#include <hip/hip_runtime.h>

using u16    = unsigned short;
using u32    = unsigned int;
using f32x4  = __attribute__((ext_vector_type(4))) float;
using f32x16 = __attribute__((ext_vector_type(16))) float;
using bf16x8 = __attribute__((ext_vector_type(8))) __bf16;
using u16x4  = __attribute__((ext_vector_type(4))) u16;
using u16x8  = __attribute__((ext_vector_type(8))) u16;
using u32x2  = __attribute__((ext_vector_type(2))) u32;
using u32x4  = __attribute__((ext_vector_type(4))) u32;
using i32x4  = __attribute__((ext_vector_type(4))) int;

// B=2, S=2048, D=1024, H=16, DK=64, M=B*S=4096.
// Softmax in exp2 domain with FIXED m=0 (normalization cancels exactly).
// KP/VP/MP packed layouts as R5-R21.
// attn R21 (best): 2 q-streams/wave, zero-barrier global-direct, (256,2).
// gemm_qkv R22: BK=32 SINGLE-BUFFERED, LDS 24KB -> 4+ blocks/CU at (256,4)
// (demand 76V+16A=92 unified <= 128 cap). Latency hidden by TLP not pipelining.

__device__ __forceinline__ u16 f2bf(float f) {
  union { __bf16 b; u16 u; } c; c.b = (__bf16)f; return c.u;
}

typedef __attribute__((address_space(1))) const void GVoid;
typedef __attribute__((address_space(3))) void LVoid;

__device__ __forceinline__ void gload_lds16(const void* g, void* l) {
  __builtin_amdgcn_global_load_lds((GVoid*)g, (LVoid*)l, 16, 0, 0);
}

// ---------------- fp32 -> bf16 conversion: WEIGHTS ONLY ----------------
__global__ void cvt_w(const float* __restrict__ a, const float* __restrict__ b,
                      const float* __restrict__ c, const float* __restrict__ dd,
                      u16* __restrict__ oa, u16* __restrict__ ob,
                      u16* __restrict__ oc, u16* __restrict__ od) {
  int y = blockIdx.y;
  const float* s = (y == 0) ? a : (y == 1) ? b : (y == 2) ? c : dd;
  u16* d = (y == 0) ? oa : (y == 1) ? ob : (y == 2) ? oc : od;
  int i = blockIdx.x * 256 + threadIdx.x;
  f32x4 v = ((const f32x4*)s)[i];
  u16x4 r;
#pragma unroll
  for (int j = 0; j < 4; ++j) r[j] = f2bf(v[j]);
  ((u16x4*)d)[i] = r;
}

// ---------------- mask bit-pack + transpose: [B,S,S] i32 -> MP[b][kt][q] u32x2 ----------------
__global__ void pack_mask(const int* __restrict__ m, u32* __restrict__ mp) {
  int tid = blockIdx.x * 256 + threadIdx.x;  // 131072 = 2*32*2048
  int q = tid & 2047, kt = (tid >> 11) & 31, b = tid >> 16;
  const i32x4* src = (const i32x4*)(m + ((size_t)(b * 2048 + q)) * 2048 + kt * 64);
  u32 w0 = 0, w1 = 0;
#pragma unroll
  for (int j = 0; j < 8; ++j) {
    i32x4 a = src[j], c = src[j + 8];
#pragma unroll
    for (int e = 0; e < 4; ++e) {
      w0 |= (a[e] != 0 ? 1u : 0u) << (j * 4 + e);
      w1 |= (c[e] != 0 ? 1u : 0u) << (j * 4 + e);
    }
  }
  ((u32x2*)mp)[((size_t)(b * 32 + kt)) * 2048 + q] = u32x2{w0, w1};
}

// ---------------- QKV GEMM: BK=32 single-buffer, 24KB LDS, 4 blocks/CU ----------------
// out[m,n] = sum_k A[m,k]*W[n,k]; z = 0/1/2 -> Q/K/V epilogue layouts.
// LDS: A fp32 [128][32] = 16KB (16B chunks, phys = logical ^ (row&7));
//      B bf16 [128][32] =  8KB at +16384 (phys = logical ^ ((row>>1)&3)).
__global__ __launch_bounds__(256, 4) void gemm_qkv(const float* __restrict__ Aq,
                                                   const float* __restrict__ Ak,
                                                   const float* __restrict__ Av,
                                                   const u16* __restrict__ Wb,
                                                   u16* __restrict__ out) {
  __shared__ alignas(16) char lds[24576];
  const int t = threadIdx.x;
  const int lane = t & 63, wid = t >> 6;
  const int g = lane >> 4, r16 = lane & 15;
  const int wm = wid >> 1, wn = wid & 1;
  const int m0 = blockIdx.x * 128, n0 = blockIdx.y * 128;
  const int z = blockIdx.z;

  const float* Axf = (z == 0) ? Aq : (z == 1) ? Ak : Av;
  const char* Ab = (const char*)Axf;
  const char* Bb = (const char*)(Wb + (size_t)z * 1048576);
  u16* op = out + (size_t)z * 4194304;
  const float qsc = (z == 0) ? 0.18033688011f : 1.0f;  // 0.125*log2(e) into Q

  f32x4 acc[4][4] = {};

  for (int kk = 0; kk < 1024; kk += 32) {
    // A tile: fp32 [128 rows][32 k] = 1024 x 16B slots, 4 async issues
#pragma unroll
    for (int i = 0; i < 4; ++i) {
      int ci = i * 256 + t;
      int row = ci >> 3;                 // 8 chunks per 128B row
      int lc = (ci & 7) ^ (row & 7);
      gload_lds16(Ab + (size_t)(m0 + row) * 4096 + kk * 4 + lc * 16, lds + ci * 16);
    }
    // B tile: bf16 [128 rows][32 k] = 512 x 16B slots, 2 async issues
#pragma unroll
    for (int i = 0; i < 2; ++i) {
      int ci = i * 256 + t;
      int row = ci >> 2;                 // 4 chunks per 64B row
      int lc = (ci & 3) ^ ((row >> 1) & 3);
      gload_lds16(Bb + (size_t)(n0 + row) * 2048 + kk * 2 + lc * 16, lds + 16384 + ci * 16);
    }
    __syncthreads();

    bf16x8 af[4], bfr[4];
#pragma unroll
    for (int mf = 0; mf < 4; ++mf) {
      int row = wm * 64 + mf * 16 + r16;
      const char* arow = lds + row * 128;
      int x = row & 7;
      f32x4 alo = *(const f32x4*)(arow + (((2 * g) ^ x) * 16));
      f32x4 ahi = *(const f32x4*)(arow + (((2 * g + 1) ^ x) * 16));
      u16x8 pk;
#pragma unroll
      for (int j = 0; j < 4; ++j) { pk[j] = f2bf(alo[j]); pk[4 + j] = f2bf(ahi[j]); }
      af[mf] = __builtin_bit_cast(bf16x8, pk);
    }
#pragma unroll
    for (int nf = 0; nf < 4; ++nf) {
      int row = wn * 64 + nf * 16 + r16;
      bfr[nf] = *(const bf16x8*)(lds + 16384 + row * 64 + ((g ^ ((row >> 1) & 3)) * 16));
    }
#pragma unroll
    for (int mf = 0; mf < 4; ++mf)
#pragma unroll
      for (int nf = 0; nf < 4; ++nf)
        acc[mf][nf] = __builtin_amdgcn_mfma_f32_16x16x32_bf16(af[mf], bfr[nf], acc[mf][nf], 0, 0, 0);

    __syncthreads();
  }

#pragma unroll
  for (int mf = 0; mf < 4; ++mf) {
#pragma unroll
    for (int nf = 0; nf < 4; ++nf) {
      int mb = m0 + wm * 64 + mf * 16 + 4 * g;
      int n = n0 + wn * 64 + nf * 16 + r16;
      if (z == 0) {  // Q: [B,H,S,DK] bf16, pre-scaled
        int bb = mb >> 11, h = n >> 6, dk = n & 63;
#pragma unroll
        for (int r = 0; r < 4; ++r) {
          int s2 = (mb + r) & 2047;
          op[((size_t)(bb * 16 + h) * 2048 + s2) * 64 + dk] = f2bf(acc[mf][nf][r] * qsc);
        }
      } else if (z == 1) {  // K packed: KP[bh][kt][half][chunk][l31] x16B
        int h = n >> 6, dk = n & 63;
#pragma unroll
        for (int r = 0; r < 4; ++r) {
          int m = mb + r;
          int bb = m >> 11, s2 = m & 2047;
          size_t off16 = ((((size_t)(bb * 16 + h) * 32 + (s2 >> 6)) * 2 + ((s2 >> 5) & 1)) * 8 +
                          (dk >> 3)) * 32 + (s2 & 31);
          op[off16 * 8 + (dk & 7)] = f2bf(acc[mf][nf][r]);
        }
      } else {  // V packed: VP[bh][kt][chunk][db][l31] x16B
        int bb = mb >> 11, s2 = mb & 2047, h = n >> 6, d = n & 63;
        size_t off16 = ((((size_t)(bb * 16 + h) * 32 + (s2 >> 6)) * 8 + ((s2 & 63) >> 3)) * 2 +
                        (d >> 5)) * 32 + (d & 31);
        u16x4 pv;
#pragma unroll
        for (int r = 0; r < 4; ++r) pv[r] = f2bf(acc[mf][nf][r]);
        *(u16x4*)(op + off16 * 8 + (s2 & 7)) = pv;
      }
    }
  }
}

// ---------------- out-projection GEMM: bf16 A (ctx), fp32 output ----------------
__global__ __launch_bounds__(256, 2) void gemm_out(const u16* __restrict__ X,
                                                   const u16* __restrict__ W,
                                                   float* __restrict__ out) {
  __shared__ alignas(16) char lds[32768];
  const int t = threadIdx.x;
  const int lane = t & 63, wid = t >> 6;
  const int g = lane >> 4, r16 = lane & 15;
  const int wm = wid >> 1, wn = wid & 1;
  const int m0 = blockIdx.x * 128, n0 = blockIdx.y * 128;
  const char* Ab = (const char*)X;
  const char* Bb = (const char*)W;

  f32x4 acc[4][4] = {};

  for (int kk = 0; kk < 1024; kk += 64) {
#pragma unroll
    for (int i = 0; i < 4; ++i) {
      int ci = i * 256 + t;
      int row = ci >> 3;
      int cbs = ((ci & 7) << 4) ^ ((row & 7) << 4);
      gload_lds16(Ab + (size_t)(m0 + row) * 2048 + kk * 2 + cbs, lds + ci * 16);
      gload_lds16(Bb + (size_t)(n0 + row) * 2048 + kk * 2 + cbs, lds + 16384 + ci * 16);
    }
    __syncthreads();
#pragma unroll
    for (int kc = 0; kc < 2; ++kc) {
      bf16x8 af[4], bfr[4];
#pragma unroll
      for (int mf = 0; mf < 4; ++mf) {
        int row = wm * 64 + mf * 16 + r16;
        af[mf] = *(const bf16x8*)(lds + row * 128 + ((64 * kc + 16 * g) ^ ((row & 7) << 4)));
      }
#pragma unroll
      for (int nf = 0; nf < 4; ++nf) {
        int row = wn * 64 + nf * 16 + r16;
        bfr[nf] = *(const bf16x8*)(lds + 16384 + row * 128 + ((64 * kc + 16 * g) ^ ((row & 7) << 4)));
      }
#pragma unroll
      for (int mf = 0; mf < 4; ++mf)
#pragma unroll
        for (int nf = 0; nf < 4; ++nf)
          acc[mf][nf] = __builtin_amdgcn_mfma_f32_16x16x32_bf16(af[mf], bfr[nf], acc[mf][nf], 0, 0, 0);
    }
    __syncthreads();
  }

#pragma unroll
  for (int mf = 0; mf < 4; ++mf)
#pragma unroll
    for (int nf = 0; nf < 4; ++nf) {
      int mb = m0 + wm * 64 + mf * 16 + 4 * g;
      int n = n0 + wn * 64 + nf * 16 + r16;
#pragma unroll
      for (int r = 0; r < 4; ++r) out[(size_t)(mb + r) * 1024 + n] = acc[mf][nf][r];
    }
}

// ---------------- flash attention: 2 q-streams/wave, zero-barrier, (256,2) ----------------
struct KH { bf16x8 k[4]; };

__device__ __forceinline__ void loadKh(KH& f, const char* p) {
#pragma unroll
  for (int c = 0; c < 4; ++c) f.k[c] = *(const bf16x8*)(p + c * 1024);
}

__device__ __forceinline__ void sm_cvt(f32x16& s, u32 wm, float& lr, u32 (&w)[8]) {
  float ps = 0.f;
#pragma unroll
  for (int r = 0; r < 16; ++r) {
    const int bit = (r & 3) + 8 * (r >> 2);
    float p = __builtin_amdgcn_exp2f(s[r]);
    int sm = ((int)(wm << (31 - bit))) >> 31;
    p = __uint_as_float(__float_as_uint(p) & (u32)sm);
    s[r] = p;
    ps += p;
  }
  lr += ps;
#pragma unroll
  for (int ss = 0; ss < 2; ++ss) {
    u32 A0, B0, A1, B1;
    asm("v_cvt_pk_bf16_f32 %0, %1, %2" : "=v"(A0) : "v"(s[8*ss+0]), "v"(s[8*ss+1]));
    asm("v_cvt_pk_bf16_f32 %0, %1, %2" : "=v"(B0) : "v"(s[8*ss+2]), "v"(s[8*ss+3]));
    asm("v_cvt_pk_bf16_f32 %0, %1, %2" : "=v"(A1) : "v"(s[8*ss+4]), "v"(s[8*ss+5]));
    asm("v_cvt_pk_bf16_f32 %0, %1, %2" : "=v"(B1) : "v"(s[8*ss+6]), "v"(s[8*ss+7]));
    asm("v_permlane32_swap_b32 %0, %1" : "+v"(A0), "+v"(A1));
    asm("v_permlane32_swap_b32 %0, %1" : "+v"(B0), "+v"(B1));
    w[4*ss+0] = A0; w[4*ss+1] = B0; w[4*ss+2] = A1; w[4*ss+3] = B1;
  }
}

__device__ __forceinline__ void attn_body(const bf16x8 (&qfa)[4], const bf16x8 (&qfb)[4],
                                          KH& cur, KH& nxt,
                                          const char*& kp, const char*& vp,
                                          const u32x2*& mpa, const u32x2*& mpb,
                                          u32x2& mca, u32x2& mcb,
                                          int kh, int hi,
                                          f32x16& oa0, f32x16& oa1,
                                          f32x16& ob0, f32x16& ob1,
                                          float& lra, float& lrb) {
  bf16x8 v00 = *(const bf16x8*)(vp);
  bf16x8 v01 = *(const bf16x8*)(vp + 512);
  bf16x8 v10 = *(const bf16x8*)(vp + 2048);
  bf16x8 v11 = *(const bf16x8*)(vp + 2560);
  loadKh(nxt, kp);
  u32x2 mna = *mpa;
  u32x2 mnb = *mpb;
  kp += 8192; vp += 8192; mpa += 2048; mpb += 2048;
  __builtin_amdgcn_sched_barrier(0);

  f32x16 sa = {}, sb = {};
#pragma unroll
  for (int c = 0; c < 4; ++c) {
    sa = __builtin_amdgcn_mfma_f32_32x32x16_bf16(cur.k[c], qfa[c], sa, 0, 0, 0);
    sb = __builtin_amdgcn_mfma_f32_32x32x16_bf16(cur.k[c], qfb[c], sb, 0, 0, 0);
  }

  u32 wma = (kh ? mca.y : mca.x) >> (4 * hi);
  u32 wmb = (kh ? mcb.y : mcb.x) >> (4 * hi);
  u32 wa[8], wb[8];
  sm_cvt(sa, wma, lra, wa);
  sm_cvt(sb, wmb, lrb, wb);

  bf16x8 pa0 = __builtin_bit_cast(bf16x8, u32x4{wa[0], wa[1], wa[2], wa[3]});
  bf16x8 pa1 = __builtin_bit_cast(bf16x8, u32x4{wa[4], wa[5], wa[6], wa[7]});
  bf16x8 pb0 = __builtin_bit_cast(bf16x8, u32x4{wb[0], wb[1], wb[2], wb[3]});
  bf16x8 pb1 = __builtin_bit_cast(bf16x8, u32x4{wb[4], wb[5], wb[6], wb[7]});
  oa0 = __builtin_amdgcn_mfma_f32_32x32x16_bf16(pa0, v00, oa0, 0, 0, 0);
  ob0 = __builtin_amdgcn_mfma_f32_32x32x16_bf16(pb0, v00, ob0, 0, 0, 0);
  oa1 = __builtin_amdgcn_mfma_f32_32x32x16_bf16(pa0, v01, oa1, 0, 0, 0);
  ob1 = __builtin_amdgcn_mfma_f32_32x32x16_bf16(pb0, v01, ob1, 0, 0, 0);
  oa0 = __builtin_amdgcn_mfma_f32_32x32x16_bf16(pa1, v10, oa0, 0, 0, 0);
  ob0 = __builtin_amdgcn_mfma_f32_32x32x16_bf16(pb1, v10, ob0, 0, 0, 0);
  oa1 = __builtin_amdgcn_mfma_f32_32x32x16_bf16(pa1, v11, oa1, 0, 0, 0);
  ob1 = __builtin_amdgcn_mfma_f32_32x32x16_bf16(pb1, v11, ob1, 0, 0, 0);
  mca = mna;
  mcb = mnb;
}

__global__ __launch_bounds__(256, 2) void attn_kern(const u16* __restrict__ Qh,
                                                    const u16* __restrict__ Kh,
                                                    const u16* __restrict__ Vt,
                                                    const u32* __restrict__ mp,
                                                    u16* __restrict__ ctx) {
  __shared__ float cmb[2][2][32][64];  // 32 KB
  __shared__ float cmbl[2][2][64];     // 1 KB
  const int t = threadIdx.x;
  const int wid = t >> 6, lane = t & 63;
  const int qw = wid & 1, kh = wid >> 1;
  const int hi = lane >> 5, l31 = lane & 31;

  const int wg = (blockIdx.x & 7) * 64 + (blockIdx.x >> 3);
  const int qt = wg & 15, bh = wg >> 4;
  const int b = bh >> 4, h = bh & 15;

  const char* qbytes = (const char*)Qh;
  const int qbase_a = qt * 128 + qw * 64;
  const int qbase_b = qbase_a + 32;
  const int qga = qbase_a + l31;
  const int qgb = qbase_b + l31;

  bf16x8 qfa[4], qfb[4];
#pragma unroll
  for (int c = 0; c < 4; ++c) {
    qfa[c] = *(const bf16x8*)(qbytes + ((size_t)bh * 2048 + qga) * 128 + 32 * c + 16 * hi);
    qfb[c] = *(const bf16x8*)(qbytes + ((size_t)bh * 2048 + qgb) * 128 + 32 * c + 16 * hi);
  }

  const char* kp = (const char*)Kh + (size_t)bh * 262144 + kh * 4096 + hi * 512 + l31 * 16;
  const char* vp = (const char*)Vt + (size_t)bh * 262144 + (size_t)(4 * kh + hi) * 1024 + l31 * 16;
  const u32x2* mpa = (const u32x2*)mp + (size_t)b * 65536 + qga;
  const u32x2* mpb = (const u32x2*)mp + (size_t)b * 65536 + qgb;

  f32x16 oa0 = {}, oa1 = {}, ob0 = {}, ob1 = {};
  float lra = 0.f, lrb = 0.f;

  KH A, B2;
  loadKh(A, kp);
  kp += 8192;
  u32x2 mca = *mpa;
  u32x2 mcb = *mpb;
  mpa += 2048; mpb += 2048;

#pragma unroll 1
  for (int it = 0; it < 16; ++it) {
    attn_body(qfa, qfb, A, B2, kp, vp, mpa, mpb, mca, mcb, kh, hi, oa0, oa1, ob0, ob1, lra, lrb);
    attn_body(qfa, qfb, B2, A, kp, vp, mpa, mpb, mca, mcb, kh, hi, oa0, oa1, ob0, ob1, lra, lrb);
  }

  lra += __shfl_xor(lra, 32, 64);
  lrb += __shfl_xor(lrb, 32, 64);

  if (kh) {
#pragma unroll
    for (int r = 0; r < 16; ++r) {
      cmb[qw][0][r][lane]      = oa0[r];
      cmb[qw][0][16 + r][lane] = oa1[r];
      cmb[qw][1][r][lane]      = ob0[r];
      cmb[qw][1][16 + r][lane] = ob1[r];
    }
    cmbl[qw][0][lane] = lra;
    cmbl[qw][1][lane] = lrb;
  }
  __syncthreads();
  if (!kh) {
#pragma unroll
    for (int r = 0; r < 16; ++r) {
      oa0[r] += cmb[qw][0][r][lane];
      oa1[r] += cmb[qw][0][16 + r][lane];
      ob0[r] += cmb[qw][1][r][lane];
      ob1[r] += cmb[qw][1][16 + r][lane];
    }
    lra += cmbl[qw][0][lane];
    lrb += cmbl[qw][1][lane];

    float rla = 1.f / lra, rlb = 1.f / lrb;
#pragma unroll
    for (int r = 0; r < 16; ++r) {
      int crow = (r & 3) + 8 * (r >> 2) + 4 * hi;
      float rva = __shfl(rla, crow, 64);
      float rvb = __shfl(rlb, crow, 64);
      size_t rowa = ((size_t)b * 2048 + qbase_a + crow) * 1024 + h * 64 + l31;
      size_t rowb = ((size_t)b * 2048 + qbase_b + crow) * 1024 + h * 64 + l31;
      ctx[rowa]      = f2bf(oa0[r] * rva);
      ctx[rowa + 32] = f2bf(oa1[r] * rva);
      ctx[rowb]      = f2bf(ob0[r] * rvb);
      ctx[rowb + 32] = f2bf(ob1[r] * rvb);
    }
  }
}

// ---------------- launch ----------------
extern "C" void kernel_launch(void* const* d_in, const int* in_sizes, int n_in,
                              void* d_out, int out_size, void* d_ws, size_t ws_size,
                              hipStream_t stream) {
  const float* q  = (const float*)d_in[0];
  const float* k  = (const float*)d_in[1];
  const float* v  = (const float*)d_in[2];
  const int* mask = (const int*)d_in[3];
  const float* Wq = (const float*)d_in[4];
  const float* Wk = (const float*)d_in[5];
  const float* Wv = (const float*)d_in[6];
  const float* Wo = (const float*)d_in[7];

  u16* ws = (u16*)d_ws;
  const size_t NX = (size_t)4096 * 1024;
  const size_t NW = (size_t)1024 * 1024;
  u16* Wqb = ws + 3 * NX;
  u16* Qh  = Wqb + 4 * NW;          // Qh | KP | VP consecutive
  u16* ctx = Qh + 3 * NX;
  u32* mpk = (u32*)ws;              // 1 MB

  cvt_w<<<dim3(1024, 4), 256, 0, stream>>>(Wq, Wk, Wv, Wo,
                                           Wqb, Wqb + NW, Wqb + 2 * NW, Wqb + 3 * NW);
  pack_mask<<<dim3(512), 256, 0, stream>>>(mask, mpk);
  gemm_qkv<<<dim3(32, 8, 3), 256, 0, stream>>>(q, k, v, Wqb, Qh);
  attn_kern<<<dim3(512), 256, 0, stream>>>(Qh, Qh + NX, Qh + 2 * NX, mpk, ctx);
  gemm_out<<<dim3(32, 8), 256, 0, stream>>>(ctx, Wqb + 3 * NW, (float*)d_out);
}

// Round 23
// 121.770 us; speedup vs baseline: 1.0294x; 1.0294x over previous
//
#include <hip/hip_runtime.h>

using u16    = unsigned short;
using u32    = unsigned int;
using f32x4  = __attribute__((ext_vector_type(4))) float;
using f32x16 = __attribute__((ext_vector_type(16))) float;
using bf16x8 = __attribute__((ext_vector_type(8))) __bf16;
using u16x4  = __attribute__((ext_vector_type(4))) u16;
using u16x8  = __attribute__((ext_vector_type(8))) u16;
using u32x2  = __attribute__((ext_vector_type(2))) u32;
using u32x4  = __attribute__((ext_vector_type(4))) u32;
using i32x4  = __attribute__((ext_vector_type(4))) int;

// B=2, S=2048, D=1024, H=16, DK=64, M=B*S=4096.
// Softmax in exp2 domain with FIXED m=0 (normalization cancels exactly).
// KP/VP/MP packed layouts as R5-R22.
// attn R21 (best): TWO independent q-streams per wave (64 q-rows) -> doubled
// intra-wave ILP on the serial QK->exp2->cvt->PV chain; K/V fragments reused x2.
// Zero-barrier global-direct loads, (256,2) proven-clean cap.
// gemm_qkv: R14 fp32-A global_load_lds structure at (256,3) (best measured).

__device__ __forceinline__ u16 f2bf(float f) {
  union { __bf16 b; u16 u; } c; c.b = (__bf16)f; return c.u;
}

typedef __attribute__((address_space(1))) const void GVoid;
typedef __attribute__((address_space(3))) void LVoid;

__device__ __forceinline__ void gload_lds16(const void* g, void* l) {
  __builtin_amdgcn_global_load_lds((GVoid*)g, (LVoid*)l, 16, 0, 0);
}

// ---------------- fp32 -> bf16 conversion: WEIGHTS ONLY ----------------
__global__ void cvt_w(const float* __restrict__ a, const float* __restrict__ b,
                      const float* __restrict__ c, const float* __restrict__ dd,
                      u16* __restrict__ oa, u16* __restrict__ ob,
                      u16* __restrict__ oc, u16* __restrict__ od) {
  int y = blockIdx.y;
  const float* s = (y == 0) ? a : (y == 1) ? b : (y == 2) ? c : dd;
  u16* d = (y == 0) ? oa : (y == 1) ? ob : (y == 2) ? oc : od;
  int i = blockIdx.x * 256 + threadIdx.x;
  f32x4 v = ((const f32x4*)s)[i];
  u16x4 r;
#pragma unroll
  for (int j = 0; j < 4; ++j) r[j] = f2bf(v[j]);
  ((u16x4*)d)[i] = r;
}

// ---------------- mask bit-pack + transpose: [B,S,S] i32 -> MP[b][kt][q] u32x2 ----------------
__global__ void pack_mask(const int* __restrict__ m, u32* __restrict__ mp) {
  int tid = blockIdx.x * 256 + threadIdx.x;  // 131072 = 2*32*2048
  int q = tid & 2047, kt = (tid >> 11) & 31, b = tid >> 16;
  const i32x4* src = (const i32x4*)(m + ((size_t)(b * 2048 + q)) * 2048 + kt * 64);
  u32 w0 = 0, w1 = 0;
#pragma unroll
  for (int j = 0; j < 8; ++j) {
    i32x4 a = src[j], c = src[j + 8];
#pragma unroll
    for (int e = 0; e < 4; ++e) {
      w0 |= (a[e] != 0 ? 1u : 0u) << (j * 4 + e);
      w1 |= (c[e] != 0 ? 1u : 0u) << (j * 4 + e);
    }
  }
  ((u32x2*)mp)[((size_t)(b * 32 + kt)) * 2048 + q] = u32x2{w0, w1};
}

// ---------------- QKV GEMM (R14/R18): A fp32 via global_load_lds ----------------
__global__ __launch_bounds__(256, 3) void gemm_qkv(const float* __restrict__ Aq,
                                                   const float* __restrict__ Ak,
                                                   const float* __restrict__ Av,
                                                   const u16* __restrict__ Wb,
                                                   u16* __restrict__ out) {
  __shared__ alignas(16) char lds[49152];
  const int t = threadIdx.x;
  const int lane = t & 63, wid = t >> 6;
  const int g = lane >> 4, r16 = lane & 15;
  const int wm = wid >> 1, wn = wid & 1;
  const int m0 = blockIdx.x * 128, n0 = blockIdx.y * 128;
  const int z = blockIdx.z;

  const float* Axf = (z == 0) ? Aq : (z == 1) ? Ak : Av;
  const char* Ab = (const char*)Axf;
  const char* Bb = (const char*)(Wb + (size_t)z * 1048576);
  u16* op = out + (size_t)z * 4194304;
  const float qsc = (z == 0) ? 0.18033688011f : 1.0f;  // 0.125*log2(e) into Q

  f32x4 acc[4][4] = {};

  for (int kk = 0; kk < 1024; kk += 64) {
#pragma unroll
    for (int i = 0; i < 8; ++i) {
      int ci = i * 256 + t;          // 16B slot
      int row = ci >> 4;
      int pc = ci & 15;
      int lc = pc ^ (row & 15);
      gload_lds16(Ab + (size_t)(m0 + row) * 4096 + kk * 4 + lc * 16, lds + ci * 16);
    }
#pragma unroll
    for (int i = 0; i < 4; ++i) {
      int ci = i * 256 + t;
      int row = ci >> 3;
      int cbs = ((ci & 7) << 4) ^ ((row & 7) << 4);
      gload_lds16(Bb + (size_t)(n0 + row) * 2048 + kk * 2 + cbs, lds + 32768 + ci * 16);
    }
    __syncthreads();
#pragma unroll
    for (int kc = 0; kc < 2; ++kc) {
      bf16x8 af[4], bfr[4];
#pragma unroll
      for (int mf = 0; mf < 4; ++mf) {
        int row = wm * 64 + mf * 16 + r16;
        const char* arow = lds + row * 256;
        int x = row & 15;
        int lc0 = 8 * kc + 2 * g;    // logical 16B chunk of k = 32kc+8g
        f32x4 alo = *(const f32x4*)(arow + ((lc0 ^ x) * 16));
        f32x4 ahi = *(const f32x4*)(arow + (((lc0 + 1) ^ x) * 16));
        u16x8 pk;
#pragma unroll
        for (int j = 0; j < 4; ++j) { pk[j] = f2bf(alo[j]); pk[4 + j] = f2bf(ahi[j]); }
        af[mf] = __builtin_bit_cast(bf16x8, pk);
      }
#pragma unroll
      for (int nf = 0; nf < 4; ++nf) {
        int row = wn * 64 + nf * 16 + r16;
        bfr[nf] = *(const bf16x8*)(lds + 32768 + row * 128 +
                                   ((64 * kc + 16 * g) ^ ((row & 7) << 4)));
      }
#pragma unroll
      for (int mf = 0; mf < 4; ++mf)
#pragma unroll
        for (int nf = 0; nf < 4; ++nf)
          acc[mf][nf] = __builtin_amdgcn_mfma_f32_16x16x32_bf16(af[mf], bfr[nf], acc[mf][nf], 0, 0, 0);
    }
    __syncthreads();
  }

#pragma unroll
  for (int mf = 0; mf < 4; ++mf) {
#pragma unroll
    for (int nf = 0; nf < 4; ++nf) {
      int mb = m0 + wm * 64 + mf * 16 + 4 * g;
      int n = n0 + wn * 64 + nf * 16 + r16;
      if (z == 0) {  // Q: [B,H,S,DK] bf16, pre-scaled
        int bb = mb >> 11, h = n >> 6, dk = n & 63;
#pragma unroll
        for (int r = 0; r < 4; ++r) {
          int s2 = (mb + r) & 2047;
          op[((size_t)(bb * 16 + h) * 2048 + s2) * 64 + dk] = f2bf(acc[mf][nf][r] * qsc);
        }
      } else if (z == 1) {  // K packed: KP[bh][kt][half][chunk][l31] x16B
        int h = n >> 6, dk = n & 63;
#pragma unroll
        for (int r = 0; r < 4; ++r) {
          int m = mb + r;
          int bb = m >> 11, s2 = m & 2047;
          size_t off16 = ((((size_t)(bb * 16 + h) * 32 + (s2 >> 6)) * 2 + ((s2 >> 5) & 1)) * 8 +
                          (dk >> 3)) * 32 + (s2 & 31);
          op[off16 * 8 + (dk & 7)] = f2bf(acc[mf][nf][r]);
        }
      } else {  // V packed: VP[bh][kt][chunk][db][l31] x16B
        int bb = mb >> 11, s2 = mb & 2047, h = n >> 6, d = n & 63;
        size_t off16 = ((((size_t)(bb * 16 + h) * 32 + (s2 >> 6)) * 8 + ((s2 & 63) >> 3)) * 2 +
                        (d >> 5)) * 32 + (d & 31);
        u16x4 pv;
#pragma unroll
        for (int r = 0; r < 4; ++r) pv[r] = f2bf(acc[mf][nf][r]);
        *(u16x4*)(op + off16 * 8 + (s2 & 7)) = pv;
      }
    }
  }
}

// ---------------- out-projection GEMM: bf16 A (ctx), fp32 output ----------------
__global__ __launch_bounds__(256, 2) void gemm_out(const u16* __restrict__ X,
                                                   const u16* __restrict__ W,
                                                   float* __restrict__ out) {
  __shared__ alignas(16) char lds[32768];
  const int t = threadIdx.x;
  const int lane = t & 63, wid = t >> 6;
  const int g = lane >> 4, r16 = lane & 15;
  const int wm = wid >> 1, wn = wid & 1;
  const int m0 = blockIdx.x * 128, n0 = blockIdx.y * 128;
  const char* Ab = (const char*)X;
  const char* Bb = (const char*)W;

  f32x4 acc[4][4] = {};

  for (int kk = 0; kk < 1024; kk += 64) {
#pragma unroll
    for (int i = 0; i < 4; ++i) {
      int ci = i * 256 + t;
      int row = ci >> 3;
      int cbs = ((ci & 7) << 4) ^ ((row & 7) << 4);
      gload_lds16(Ab + (size_t)(m0 + row) * 2048 + kk * 2 + cbs, lds + ci * 16);
      gload_lds16(Bb + (size_t)(n0 + row) * 2048 + kk * 2 + cbs, lds + 16384 + ci * 16);
    }
    __syncthreads();
#pragma unroll
    for (int kc = 0; kc < 2; ++kc) {
      bf16x8 af[4], bfr[4];
#pragma unroll
      for (int mf = 0; mf < 4; ++mf) {
        int row = wm * 64 + mf * 16 + r16;
        af[mf] = *(const bf16x8*)(lds + row * 128 + ((64 * kc + 16 * g) ^ ((row & 7) << 4)));
      }
#pragma unroll
      for (int nf = 0; nf < 4; ++nf) {
        int row = wn * 64 + nf * 16 + r16;
        bfr[nf] = *(const bf16x8*)(lds + 16384 + row * 128 + ((64 * kc + 16 * g) ^ ((row & 7) << 4)));
      }
#pragma unroll
      for (int mf = 0; mf < 4; ++mf)
#pragma unroll
        for (int nf = 0; nf < 4; ++nf)
          acc[mf][nf] = __builtin_amdgcn_mfma_f32_16x16x32_bf16(af[mf], bfr[nf], acc[mf][nf], 0, 0, 0);
    }
    __syncthreads();
  }

#pragma unroll
  for (int mf = 0; mf < 4; ++mf)
#pragma unroll
    for (int nf = 0; nf < 4; ++nf) {
      int mb = m0 + wm * 64 + mf * 16 + 4 * g;
      int n = n0 + wn * 64 + nf * 16 + r16;
#pragma unroll
      for (int r = 0; r < 4; ++r) out[(size_t)(mb + r) * 1024 + n] = acc[mf][nf][r];
    }
}

// ---------------- flash attention: 2 q-streams/wave, zero-barrier, (256,2) ----------------
struct KH { bf16x8 k[4]; };

__device__ __forceinline__ void loadKh(KH& f, const char* p) {
#pragma unroll
  for (int c = 0; c < 4; ++c) f.k[c] = *(const bf16x8*)(p + c * 1024);
}

__device__ __forceinline__ void sm_cvt(f32x16& s, u32 wm, float& lr, u32 (&w)[8]) {
  float ps = 0.f;
#pragma unroll
  for (int r = 0; r < 16; ++r) {
    const int bit = (r & 3) + 8 * (r >> 2);
    float p = __builtin_amdgcn_exp2f(s[r]);
    int sm = ((int)(wm << (31 - bit))) >> 31;
    p = __uint_as_float(__float_as_uint(p) & (u32)sm);
    s[r] = p;
    ps += p;
  }
  lr += ps;
#pragma unroll
  for (int ss = 0; ss < 2; ++ss) {
    u32 A0, B0, A1, B1;
    asm("v_cvt_pk_bf16_f32 %0, %1, %2" : "=v"(A0) : "v"(s[8*ss+0]), "v"(s[8*ss+1]));
    asm("v_cvt_pk_bf16_f32 %0, %1, %2" : "=v"(B0) : "v"(s[8*ss+2]), "v"(s[8*ss+3]));
    asm("v_cvt_pk_bf16_f32 %0, %1, %2" : "=v"(A1) : "v"(s[8*ss+4]), "v"(s[8*ss+5]));
    asm("v_cvt_pk_bf16_f32 %0, %1, %2" : "=v"(B1) : "v"(s[8*ss+6]), "v"(s[8*ss+7]));
    asm("v_permlane32_swap_b32 %0, %1" : "+v"(A0), "+v"(A1));
    asm("v_permlane32_swap_b32 %0, %1" : "+v"(B0), "+v"(B1));
    w[4*ss+0] = A0; w[4*ss+1] = B0; w[4*ss+2] = A1; w[4*ss+3] = B1;
  }
}

__device__ __forceinline__ void attn_body(const bf16x8 (&qfa)[4], const bf16x8 (&qfb)[4],
                                          KH& cur, KH& nxt,
                                          const char*& kp, const char*& vp,
                                          const u32x2*& mpa, const u32x2*& mpb,
                                          u32x2& mca, u32x2& mcb,
                                          int kh, int hi,
                                          f32x16& oa0, f32x16& oa1,
                                          f32x16& ob0, f32x16& ob1,
                                          float& lra, float& lrb) {
  // V for CURRENT tile (shared by both q-streams)
  bf16x8 v00 = *(const bf16x8*)(vp);
  bf16x8 v01 = *(const bf16x8*)(vp + 512);
  bf16x8 v10 = *(const bf16x8*)(vp + 2048);
  bf16x8 v11 = *(const bf16x8*)(vp + 2560);
  // K + masks for NEXT tile (explicit dbuf)
  loadKh(nxt, kp);
  u32x2 mna = *mpa;
  u32x2 mnb = *mpb;
  kp += 8192; vp += 8192; mpa += 2048; mpb += 2048;
  __builtin_amdgcn_sched_barrier(0);  // pin load issue above compute

  // QK^T: two independent chains
  f32x16 sa = {}, sb = {};
#pragma unroll
  for (int c = 0; c < 4; ++c) {
    sa = __builtin_amdgcn_mfma_f32_32x32x16_bf16(cur.k[c], qfa[c], sa, 0, 0, 0);
    sb = __builtin_amdgcn_mfma_f32_32x32x16_bf16(cur.k[c], qfb[c], sb, 0, 0, 0);
  }

  u32 wma = (kh ? mca.y : mca.x) >> (4 * hi);
  u32 wmb = (kh ? mcb.y : mcb.x) >> (4 * hi);
  u32 wa[8], wb[8];
  sm_cvt(sa, wma, lra, wa);
  sm_cvt(sb, wmb, lrb, wb);

  // PV: both streams consume the same V fragments
  bf16x8 pa0 = __builtin_bit_cast(bf16x8, u32x4{wa[0], wa[1], wa[2], wa[3]});
  bf16x8 pa1 = __builtin_bit_cast(bf16x8, u32x4{wa[4], wa[5], wa[6], wa[7]});
  bf16x8 pb0 = __builtin_bit_cast(bf16x8, u32x4{wb[0], wb[1], wb[2], wb[3]});
  bf16x8 pb1 = __builtin_bit_cast(bf16x8, u32x4{wb[4], wb[5], wb[6], wb[7]});
  oa0 = __builtin_amdgcn_mfma_f32_32x32x16_bf16(pa0, v00, oa0, 0, 0, 0);
  ob0 = __builtin_amdgcn_mfma_f32_32x32x16_bf16(pb0, v00, ob0, 0, 0, 0);
  oa1 = __builtin_amdgcn_mfma_f32_32x32x16_bf16(pa0, v01, oa1, 0, 0, 0);
  ob1 = __builtin_amdgcn_mfma_f32_32x32x16_bf16(pb0, v01, ob1, 0, 0, 0);
  oa0 = __builtin_amdgcn_mfma_f32_32x32x16_bf16(pa1, v10, oa0, 0, 0, 0);
  ob0 = __builtin_amdgcn_mfma_f32_32x32x16_bf16(pb1, v10, ob0, 0, 0, 0);
  oa1 = __builtin_amdgcn_mfma_f32_32x32x16_bf16(pa1, v11, oa1, 0, 0, 0);
  ob1 = __builtin_amdgcn_mfma_f32_32x32x16_bf16(pb1, v11, ob1, 0, 0, 0);
  mca = mna;
  mcb = mnb;
}

__global__ __launch_bounds__(256, 2) void attn_kern(const u16* __restrict__ Qh,
                                                    const u16* __restrict__ Kh,
                                                    const u16* __restrict__ Vt,
                                                    const u32* __restrict__ mp,
                                                    u16* __restrict__ ctx) {
  __shared__ float cmb[2][2][32][64];  // 32 KB: kh=1 partials per (qw, stream)
  __shared__ float cmbl[2][2][64];     // 1 KB
  const int t = threadIdx.x;
  const int wid = t >> 6, lane = t & 63;
  const int qw = wid & 1, kh = wid >> 1;
  const int hi = lane >> 5, l31 = lane & 31;

  // XCD-aware swizzle: 512 blocks, 64-block chunk per XCD
  const int wg = (blockIdx.x & 7) * 64 + (blockIdx.x >> 3);
  const int qt = wg & 15, bh = wg >> 4;
  const int b = bh >> 4, h = bh & 15;

  const char* qbytes = (const char*)Qh;
  const int qbase_a = qt * 128 + qw * 64;        // stream a: 32 rows
  const int qbase_b = qbase_a + 32;              // stream b: next 32 rows
  const int qga = qbase_a + l31;
  const int qgb = qbase_b + l31;

  bf16x8 qfa[4], qfb[4];
#pragma unroll
  for (int c = 0; c < 4; ++c) {
    qfa[c] = *(const bf16x8*)(qbytes + ((size_t)bh * 2048 + qga) * 128 + 32 * c + 16 * hi);
    qfb[c] = *(const bf16x8*)(qbytes + ((size_t)bh * 2048 + qgb) * 128 + 32 * c + 16 * hi);
  }

  const char* kp = (const char*)Kh + (size_t)bh * 262144 + kh * 4096 + hi * 512 + l31 * 16;
  const char* vp = (const char*)Vt + (size_t)bh * 262144 + (size_t)(4 * kh + hi) * 1024 + l31 * 16;
  const u32x2* mpa = (const u32x2*)mp + (size_t)b * 65536 + qga;
  const u32x2* mpb = (const u32x2*)mp + (size_t)b * 65536 + qgb;

  f32x16 oa0 = {}, oa1 = {}, ob0 = {}, ob1 = {};
  float lra = 0.f, lrb = 0.f;

  KH A, B2;
  loadKh(A, kp);
  kp += 8192;
  u32x2 mca = *mpa;
  u32x2 mcb = *mpb;
  mpa += 2048; mpb += 2048;

#pragma unroll 1
  for (int it = 0; it < 16; ++it) {   // 32 tiles, 2 bodies/iter
    attn_body(qfa, qfb, A, B2, kp, vp, mpa, mpb, mca, mcb, kh, hi, oa0, oa1, ob0, ob1, lra, lrb);
    attn_body(qfa, qfb, B2, A, kp, vp, mpa, mpb, mca, mcb, kh, hi, oa0, oa1, ob0, ob1, lra, lrb);
  }

  lra += __shfl_xor(lra, 32, 64);
  lrb += __shfl_xor(lrb, 32, 64);

  // split-K combine: kh=1 publishes, kh=0 adds + stores (both streams)
  if (kh) {
#pragma unroll
    for (int r = 0; r < 16; ++r) {
      cmb[qw][0][r][lane]      = oa0[r];
      cmb[qw][0][16 + r][lane] = oa1[r];
      cmb[qw][1][r][lane]      = ob0[r];
      cmb[qw][1][16 + r][lane] = ob1[r];
    }
    cmbl[qw][0][lane] = lra;
    cmbl[qw][1][lane] = lrb;
  }
  __syncthreads();
  if (!kh) {
#pragma unroll
    for (int r = 0; r < 16; ++r) {
      oa0[r] += cmb[qw][0][r][lane];
      oa1[r] += cmb[qw][0][16 + r][lane];
      ob0[r] += cmb[qw][1][r][lane];
      ob1[r] += cmb[qw][1][16 + r][lane];
    }
    lra += cmbl[qw][0][lane];
    lrb += cmbl[qw][1][lane];

    float rla = 1.f / lra, rlb = 1.f / lrb;
#pragma unroll
    for (int r = 0; r < 16; ++r) {
      int crow = (r & 3) + 8 * (r >> 2) + 4 * hi;
      float rva = __shfl(rla, crow, 64);
      float rvb = __shfl(rlb, crow, 64);
      size_t rowa = ((size_t)b * 2048 + qbase_a + crow) * 1024 + h * 64 + l31;
      size_t rowb = ((size_t)b * 2048 + qbase_b + crow) * 1024 + h * 64 + l31;
      ctx[rowa]      = f2bf(oa0[r] * rva);
      ctx[rowa + 32] = f2bf(oa1[r] * rva);
      ctx[rowb]      = f2bf(ob0[r] * rvb);
      ctx[rowb + 32] = f2bf(ob1[r] * rvb);
    }
  }
}

// ---------------- launch ----------------
extern "C" void kernel_launch(void* const* d_in, const int* in_sizes, int n_in,
                              void* d_out, int out_size, void* d_ws, size_t ws_size,
                              hipStream_t stream) {
  const float* q  = (const float*)d_in[0];
  const float* k  = (const float*)d_in[1];
  const float* v  = (const float*)d_in[2];
  const int* mask = (const int*)d_in[3];
  const float* Wq = (const float*)d_in[4];
  const float* Wk = (const float*)d_in[5];
  const float* Wv = (const float*)d_in[6];
  const float* Wo = (const float*)d_in[7];

  u16* ws = (u16*)d_ws;
  const size_t NX = (size_t)4096 * 1024;
  const size_t NW = (size_t)1024 * 1024;
  u16* Wqb = ws + 3 * NX;
  u16* Qh  = Wqb + 4 * NW;          // Qh | KP | VP consecutive
  u16* ctx = Qh + 3 * NX;
  u32* mpk = (u32*)ws;              // 1 MB

  cvt_w<<<dim3(1024, 4), 256, 0, stream>>>(Wq, Wk, Wv, Wo,
                                           Wqb, Wqb + NW, Wqb + 2 * NW, Wqb + 3 * NW);
  pack_mask<<<dim3(512), 256, 0, stream>>>(mask, mpk);
  gemm_qkv<<<dim3(32, 8, 3), 256, 0, stream>>>(q, k, v, Wqb, Qh);
  attn_kern<<<dim3(512), 256, 0, stream>>>(Qh, Qh + NX, Qh + 2 * NX, mpk, ctx);
  gemm_out<<<dim3(32, 8), 256, 0, stream>>>(ctx, Wqb + 3 * NW, (float*)d_out);
}

// Round 24
// 119.199 us; speedup vs baseline: 1.0516x; 1.0216x over previous
//
#include <hip/hip_runtime.h>

using u16    = unsigned short;
using u32    = unsigned int;
using f32x4  = __attribute__((ext_vector_type(4))) float;
using f32x16 = __attribute__((ext_vector_type(16))) float;
using bf16x8 = __attribute__((ext_vector_type(8))) __bf16;
using u16x4  = __attribute__((ext_vector_type(4))) u16;
using u16x8  = __attribute__((ext_vector_type(8))) u16;
using u32x2  = __attribute__((ext_vector_type(2))) u32;
using u32x4  = __attribute__((ext_vector_type(4))) u32;
using i32x4  = __attribute__((ext_vector_type(4))) int;

// B=2, S=2048, D=1024, H=16, DK=64, M=B*S=4096.
// Softmax in exp2 domain with FIXED m=0 (normalization cancels exactly).
// KP/VP/MP packed layouts as R5-R23.
// attn R21 (best): two q-streams/wave, zero-barrier global-direct, (256,2).
// gemm_qkv: R14 fp32-A global_load_lds structure at (256,3) (best measured).
// gemm_out R24: BM=64 tiles -> 512 blocks = 2 blocks/CU (was 256 = 1/CU,
// latency-starved); waves 1x4, acc 4x2, LDS 24KB, same proven swizzles.

__device__ __forceinline__ u16 f2bf(float f) {
  union { __bf16 b; u16 u; } c; c.b = (__bf16)f; return c.u;
}

typedef __attribute__((address_space(1))) const void GVoid;
typedef __attribute__((address_space(3))) void LVoid;

__device__ __forceinline__ void gload_lds16(const void* g, void* l) {
  __builtin_amdgcn_global_load_lds((GVoid*)g, (LVoid*)l, 16, 0, 0);
}

// ---------------- fp32 -> bf16 conversion: WEIGHTS ONLY ----------------
__global__ void cvt_w(const float* __restrict__ a, const float* __restrict__ b,
                      const float* __restrict__ c, const float* __restrict__ dd,
                      u16* __restrict__ oa, u16* __restrict__ ob,
                      u16* __restrict__ oc, u16* __restrict__ od) {
  int y = blockIdx.y;
  const float* s = (y == 0) ? a : (y == 1) ? b : (y == 2) ? c : dd;
  u16* d = (y == 0) ? oa : (y == 1) ? ob : (y == 2) ? oc : od;
  int i = blockIdx.x * 256 + threadIdx.x;
  f32x4 v = ((const f32x4*)s)[i];
  u16x4 r;
#pragma unroll
  for (int j = 0; j < 4; ++j) r[j] = f2bf(v[j]);
  ((u16x4*)d)[i] = r;
}

// ---------------- mask bit-pack + transpose: [B,S,S] i32 -> MP[b][kt][q] u32x2 ----------------
__global__ void pack_mask(const int* __restrict__ m, u32* __restrict__ mp) {
  int tid = blockIdx.x * 256 + threadIdx.x;  // 131072 = 2*32*2048
  int q = tid & 2047, kt = (tid >> 11) & 31, b = tid >> 16;
  const i32x4* src = (const i32x4*)(m + ((size_t)(b * 2048 + q)) * 2048 + kt * 64);
  u32 w0 = 0, w1 = 0;
#pragma unroll
  for (int j = 0; j < 8; ++j) {
    i32x4 a = src[j], c = src[j + 8];
#pragma unroll
    for (int e = 0; e < 4; ++e) {
      w0 |= (a[e] != 0 ? 1u : 0u) << (j * 4 + e);
      w1 |= (c[e] != 0 ? 1u : 0u) << (j * 4 + e);
    }
  }
  ((u32x2*)mp)[((size_t)(b * 32 + kt)) * 2048 + q] = u32x2{w0, w1};
}

// ---------------- QKV GEMM (R14/R18): A fp32 via global_load_lds ----------------
__global__ __launch_bounds__(256, 3) void gemm_qkv(const float* __restrict__ Aq,
                                                   const float* __restrict__ Ak,
                                                   const float* __restrict__ Av,
                                                   const u16* __restrict__ Wb,
                                                   u16* __restrict__ out) {
  __shared__ alignas(16) char lds[49152];
  const int t = threadIdx.x;
  const int lane = t & 63, wid = t >> 6;
  const int g = lane >> 4, r16 = lane & 15;
  const int wm = wid >> 1, wn = wid & 1;
  const int m0 = blockIdx.x * 128, n0 = blockIdx.y * 128;
  const int z = blockIdx.z;

  const float* Axf = (z == 0) ? Aq : (z == 1) ? Ak : Av;
  const char* Ab = (const char*)Axf;
  const char* Bb = (const char*)(Wb + (size_t)z * 1048576);
  u16* op = out + (size_t)z * 4194304;
  const float qsc = (z == 0) ? 0.18033688011f : 1.0f;  // 0.125*log2(e) into Q

  f32x4 acc[4][4] = {};

  for (int kk = 0; kk < 1024; kk += 64) {
#pragma unroll
    for (int i = 0; i < 8; ++i) {
      int ci = i * 256 + t;          // 16B slot
      int row = ci >> 4;
      int pc = ci & 15;
      int lc = pc ^ (row & 15);
      gload_lds16(Ab + (size_t)(m0 + row) * 4096 + kk * 4 + lc * 16, lds + ci * 16);
    }
#pragma unroll
    for (int i = 0; i < 4; ++i) {
      int ci = i * 256 + t;
      int row = ci >> 3;
      int cbs = ((ci & 7) << 4) ^ ((row & 7) << 4);
      gload_lds16(Bb + (size_t)(n0 + row) * 2048 + kk * 2 + cbs, lds + 32768 + ci * 16);
    }
    __syncthreads();
#pragma unroll
    for (int kc = 0; kc < 2; ++kc) {
      bf16x8 af[4], bfr[4];
#pragma unroll
      for (int mf = 0; mf < 4; ++mf) {
        int row = wm * 64 + mf * 16 + r16;
        const char* arow = lds + row * 256;
        int x = row & 15;
        int lc0 = 8 * kc + 2 * g;    // logical 16B chunk of k = 32kc+8g
        f32x4 alo = *(const f32x4*)(arow + ((lc0 ^ x) * 16));
        f32x4 ahi = *(const f32x4*)(arow + (((lc0 + 1) ^ x) * 16));
        u16x8 pk;
#pragma unroll
        for (int j = 0; j < 4; ++j) { pk[j] = f2bf(alo[j]); pk[4 + j] = f2bf(ahi[j]); }
        af[mf] = __builtin_bit_cast(bf16x8, pk);
      }
#pragma unroll
      for (int nf = 0; nf < 4; ++nf) {
        int row = wn * 64 + nf * 16 + r16;
        bfr[nf] = *(const bf16x8*)(lds + 32768 + row * 128 +
                                   ((64 * kc + 16 * g) ^ ((row & 7) << 4)));
      }
#pragma unroll
      for (int mf = 0; mf < 4; ++mf)
#pragma unroll
        for (int nf = 0; nf < 4; ++nf)
          acc[mf][nf] = __builtin_amdgcn_mfma_f32_16x16x32_bf16(af[mf], bfr[nf], acc[mf][nf], 0, 0, 0);
    }
    __syncthreads();
  }

#pragma unroll
  for (int mf = 0; mf < 4; ++mf) {
#pragma unroll
    for (int nf = 0; nf < 4; ++nf) {
      int mb = m0 + wm * 64 + mf * 16 + 4 * g;
      int n = n0 + wn * 64 + nf * 16 + r16;
      if (z == 0) {  // Q: [B,H,S,DK] bf16, pre-scaled
        int bb = mb >> 11, h = n >> 6, dk = n & 63;
#pragma unroll
        for (int r = 0; r < 4; ++r) {
          int s2 = (mb + r) & 2047;
          op[((size_t)(bb * 16 + h) * 2048 + s2) * 64 + dk] = f2bf(acc[mf][nf][r] * qsc);
        }
      } else if (z == 1) {  // K packed: KP[bh][kt][half][chunk][l31] x16B
        int h = n >> 6, dk = n & 63;
#pragma unroll
        for (int r = 0; r < 4; ++r) {
          int m = mb + r;
          int bb = m >> 11, s2 = m & 2047;
          size_t off16 = ((((size_t)(bb * 16 + h) * 32 + (s2 >> 6)) * 2 + ((s2 >> 5) & 1)) * 8 +
                          (dk >> 3)) * 32 + (s2 & 31);
          op[off16 * 8 + (dk & 7)] = f2bf(acc[mf][nf][r]);
        }
      } else {  // V packed: VP[bh][kt][chunk][db][l31] x16B
        int bb = mb >> 11, s2 = mb & 2047, h = n >> 6, d = n & 63;
        size_t off16 = ((((size_t)(bb * 16 + h) * 32 + (s2 >> 6)) * 8 + ((s2 & 63) >> 3)) * 2 +
                        (d >> 5)) * 32 + (d & 31);
        u16x4 pv;
#pragma unroll
        for (int r = 0; r < 4; ++r) pv[r] = f2bf(acc[mf][nf][r]);
        *(u16x4*)(op + off16 * 8 + (s2 & 7)) = pv;
      }
    }
  }
}

// ---------------- out-projection GEMM: BM=64 tiles, 512 blocks = 2/CU ----------------
// 4 waves arranged 1x4: wave wid owns all 64 rows x cols [wid*32, wid*32+32).
__global__ __launch_bounds__(256, 2) void gemm_out(const u16* __restrict__ X,
                                                   const u16* __restrict__ W,
                                                   float* __restrict__ out) {
  __shared__ alignas(16) char lds[24576];  // A bf16 [64][64] 8KB | B bf16 [128][64] 16KB
  const int t = threadIdx.x;
  const int lane = t & 63, wid = t >> 6;
  const int g = lane >> 4, r16 = lane & 15;
  const int m0 = blockIdx.x * 64, n0 = blockIdx.y * 128;
  const char* Ab = (const char*)X;
  const char* Bb = (const char*)W;

  f32x4 acc[4][2] = {};

  for (int kk = 0; kk < 1024; kk += 64) {
    // A tile: 64 rows x 128B = 512 slots, 2 async issues (proven swizzle)
#pragma unroll
    for (int i = 0; i < 2; ++i) {
      int ci = i * 256 + t;
      int row = ci >> 3;
      int cbs = ((ci & 7) << 4) ^ ((row & 7) << 4);
      gload_lds16(Ab + (size_t)(m0 + row) * 2048 + kk * 2 + cbs, lds + ci * 16);
    }
    // B tile: 128 rows x 128B = 1024 slots, 4 async issues
#pragma unroll
    for (int i = 0; i < 4; ++i) {
      int ci = i * 256 + t;
      int row = ci >> 3;
      int cbs = ((ci & 7) << 4) ^ ((row & 7) << 4);
      gload_lds16(Bb + (size_t)(n0 + row) * 2048 + kk * 2 + cbs, lds + 8192 + ci * 16);
    }
    __syncthreads();
#pragma unroll
    for (int kc = 0; kc < 2; ++kc) {
      bf16x8 af[4], bfr[2];
#pragma unroll
      for (int mf = 0; mf < 4; ++mf) {
        int row = mf * 16 + r16;
        af[mf] = *(const bf16x8*)(lds + row * 128 + ((64 * kc + 16 * g) ^ ((row & 7) << 4)));
      }
#pragma unroll
      for (int nf = 0; nf < 2; ++nf) {
        int row = wid * 32 + nf * 16 + r16;
        bfr[nf] = *(const bf16x8*)(lds + 8192 + row * 128 + ((64 * kc + 16 * g) ^ ((row & 7) << 4)));
      }
#pragma unroll
      for (int mf = 0; mf < 4; ++mf)
#pragma unroll
        for (int nf = 0; nf < 2; ++nf)
          acc[mf][nf] = __builtin_amdgcn_mfma_f32_16x16x32_bf16(af[mf], bfr[nf], acc[mf][nf], 0, 0, 0);
    }
    __syncthreads();
  }

#pragma unroll
  for (int mf = 0; mf < 4; ++mf)
#pragma unroll
    for (int nf = 0; nf < 2; ++nf) {
      int mb = m0 + mf * 16 + 4 * g;
      int n = n0 + wid * 32 + nf * 16 + r16;
#pragma unroll
      for (int r = 0; r < 4; ++r) out[(size_t)(mb + r) * 1024 + n] = acc[mf][nf][r];
    }
}

// ---------------- flash attention: 2 q-streams/wave, zero-barrier, (256,2) ----------------
struct KH { bf16x8 k[4]; };

__device__ __forceinline__ void loadKh(KH& f, const char* p) {
#pragma unroll
  for (int c = 0; c < 4; ++c) f.k[c] = *(const bf16x8*)(p + c * 1024);
}

__device__ __forceinline__ void sm_cvt(f32x16& s, u32 wm, float& lr, u32 (&w)[8]) {
  float ps = 0.f;
#pragma unroll
  for (int r = 0; r < 16; ++r) {
    const int bit = (r & 3) + 8 * (r >> 2);
    float p = __builtin_amdgcn_exp2f(s[r]);
    int sm = ((int)(wm << (31 - bit))) >> 31;
    p = __uint_as_float(__float_as_uint(p) & (u32)sm);
    s[r] = p;
    ps += p;
  }
  lr += ps;
#pragma unroll
  for (int ss = 0; ss < 2; ++ss) {
    u32 A0, B0, A1, B1;
    asm("v_cvt_pk_bf16_f32 %0, %1, %2" : "=v"(A0) : "v"(s[8*ss+0]), "v"(s[8*ss+1]));
    asm("v_cvt_pk_bf16_f32 %0, %1, %2" : "=v"(B0) : "v"(s[8*ss+2]), "v"(s[8*ss+3]));
    asm("v_cvt_pk_bf16_f32 %0, %1, %2" : "=v"(A1) : "v"(s[8*ss+4]), "v"(s[8*ss+5]));
    asm("v_cvt_pk_bf16_f32 %0, %1, %2" : "=v"(B1) : "v"(s[8*ss+6]), "v"(s[8*ss+7]));
    asm("v_permlane32_swap_b32 %0, %1" : "+v"(A0), "+v"(A1));
    asm("v_permlane32_swap_b32 %0, %1" : "+v"(B0), "+v"(B1));
    w[4*ss+0] = A0; w[4*ss+1] = B0; w[4*ss+2] = A1; w[4*ss+3] = B1;
  }
}

__device__ __forceinline__ void attn_body(const bf16x8 (&qfa)[4], const bf16x8 (&qfb)[4],
                                          KH& cur, KH& nxt,
                                          const char*& kp, const char*& vp,
                                          const u32x2*& mpa, const u32x2*& mpb,
                                          u32x2& mca, u32x2& mcb,
                                          int kh, int hi,
                                          f32x16& oa0, f32x16& oa1,
                                          f32x16& ob0, f32x16& ob1,
                                          float& lra, float& lrb) {
  // V for CURRENT tile (shared by both q-streams)
  bf16x8 v00 = *(const bf16x8*)(vp);
  bf16x8 v01 = *(const bf16x8*)(vp + 512);
  bf16x8 v10 = *(const bf16x8*)(vp + 2048);
  bf16x8 v11 = *(const bf16x8*)(vp + 2560);
  // K + masks for NEXT tile (explicit dbuf)
  loadKh(nxt, kp);
  u32x2 mna = *mpa;
  u32x2 mnb = *mpb;
  kp += 8192; vp += 8192; mpa += 2048; mpb += 2048;
  __builtin_amdgcn_sched_barrier(0);  // pin load issue above compute

  // QK^T: two independent chains
  f32x16 sa = {}, sb = {};
#pragma unroll
  for (int c = 0; c < 4; ++c) {
    sa = __builtin_amdgcn_mfma_f32_32x32x16_bf16(cur.k[c], qfa[c], sa, 0, 0, 0);
    sb = __builtin_amdgcn_mfma_f32_32x32x16_bf16(cur.k[c], qfb[c], sb, 0, 0, 0);
  }

  u32 wma = (kh ? mca.y : mca.x) >> (4 * hi);
  u32 wmb = (kh ? mcb.y : mcb.x) >> (4 * hi);
  u32 wa[8], wb[8];
  sm_cvt(sa, wma, lra, wa);
  sm_cvt(sb, wmb, lrb, wb);

  // PV: both streams consume the same V fragments
  bf16x8 pa0 = __builtin_bit_cast(bf16x8, u32x4{wa[0], wa[1], wa[2], wa[3]});
  bf16x8 pa1 = __builtin_bit_cast(bf16x8, u32x4{wa[4], wa[5], wa[6], wa[7]});
  bf16x8 pb0 = __builtin_bit_cast(bf16x8, u32x4{wb[0], wb[1], wb[2], wb[3]});
  bf16x8 pb1 = __builtin_bit_cast(bf16x8, u32x4{wb[4], wb[5], wb[6], wb[7]});
  oa0 = __builtin_amdgcn_mfma_f32_32x32x16_bf16(pa0, v00, oa0, 0, 0, 0);
  ob0 = __builtin_amdgcn_mfma_f32_32x32x16_bf16(pb0, v00, ob0, 0, 0, 0);
  oa1 = __builtin_amdgcn_mfma_f32_32x32x16_bf16(pa0, v01, oa1, 0, 0, 0);
  ob1 = __builtin_amdgcn_mfma_f32_32x32x16_bf16(pb0, v01, ob1, 0, 0, 0);
  oa0 = __builtin_amdgcn_mfma_f32_32x32x16_bf16(pa1, v10, oa0, 0, 0, 0);
  ob0 = __builtin_amdgcn_mfma_f32_32x32x16_bf16(pb1, v10, ob0, 0, 0, 0);
  oa1 = __builtin_amdgcn_mfma_f32_32x32x16_bf16(pa1, v11, oa1, 0, 0, 0);
  ob1 = __builtin_amdgcn_mfma_f32_32x32x16_bf16(pb1, v11, ob1, 0, 0, 0);
  mca = mna;
  mcb = mnb;
}

__global__ __launch_bounds__(256, 2) void attn_kern(const u16* __restrict__ Qh,
                                                    const u16* __restrict__ Kh,
                                                    const u16* __restrict__ Vt,
                                                    const u32* __restrict__ mp,
                                                    u16* __restrict__ ctx) {
  __shared__ float cmb[2][2][32][64];  // 32 KB: kh=1 partials per (qw, stream)
  __shared__ float cmbl[2][2][64];     // 1 KB
  const int t = threadIdx.x;
  const int wid = t >> 6, lane = t & 63;
  const int qw = wid & 1, kh = wid >> 1;
  const int hi = lane >> 5, l31 = lane & 31;

  // XCD-aware swizzle: 512 blocks, 64-block chunk per XCD
  const int wg = (blockIdx.x & 7) * 64 + (blockIdx.x >> 3);
  const int qt = wg & 15, bh = wg >> 4;
  const int b = bh >> 4, h = bh & 15;

  const char* qbytes = (const char*)Qh;
  const int qbase_a = qt * 128 + qw * 64;        // stream a: 32 rows
  const int qbase_b = qbase_a + 32;              // stream b: next 32 rows
  const int qga = qbase_a + l31;
  const int qgb = qbase_b + l31;

  bf16x8 qfa[4], qfb[4];
#pragma unroll
  for (int c = 0; c < 4; ++c) {
    qfa[c] = *(const bf16x8*)(qbytes + ((size_t)bh * 2048 + qga) * 128 + 32 * c + 16 * hi);
    qfb[c] = *(const bf16x8*)(qbytes + ((size_t)bh * 2048 + qgb) * 128 + 32 * c + 16 * hi);
  }

  const char* kp = (const char*)Kh + (size_t)bh * 262144 + kh * 4096 + hi * 512 + l31 * 16;
  const char* vp = (const char*)Vt + (size_t)bh * 262144 + (size_t)(4 * kh + hi) * 1024 + l31 * 16;
  const u32x2* mpa = (const u32x2*)mp + (size_t)b * 65536 + qga;
  const u32x2* mpb = (const u32x2*)mp + (size_t)b * 65536 + qgb;

  f32x16 oa0 = {}, oa1 = {}, ob0 = {}, ob1 = {};
  float lra = 0.f, lrb = 0.f;

  KH A, B2;
  loadKh(A, kp);
  kp += 8192;
  u32x2 mca = *mpa;
  u32x2 mcb = *mpb;
  mpa += 2048; mpb += 2048;

#pragma unroll 1
  for (int it = 0; it < 16; ++it) {   // 32 tiles, 2 bodies/iter
    attn_body(qfa, qfb, A, B2, kp, vp, mpa, mpb, mca, mcb, kh, hi, oa0, oa1, ob0, ob1, lra, lrb);
    attn_body(qfa, qfb, B2, A, kp, vp, mpa, mpb, mca, mcb, kh, hi, oa0, oa1, ob0, ob1, lra, lrb);
  }

  lra += __shfl_xor(lra, 32, 64);
  lrb += __shfl_xor(lrb, 32, 64);

  // split-K combine: kh=1 publishes, kh=0 adds + stores (both streams)
  if (kh) {
#pragma unroll
    for (int r = 0; r < 16; ++r) {
      cmb[qw][0][r][lane]      = oa0[r];
      cmb[qw][0][16 + r][lane] = oa1[r];
      cmb[qw][1][r][lane]      = ob0[r];
      cmb[qw][1][16 + r][lane] = ob1[r];
    }
    cmbl[qw][0][lane] = lra;
    cmbl[qw][1][lane] = lrb;
  }
  __syncthreads();
  if (!kh) {
#pragma unroll
    for (int r = 0; r < 16; ++r) {
      oa0[r] += cmb[qw][0][r][lane];
      oa1[r] += cmb[qw][0][16 + r][lane];
      ob0[r] += cmb[qw][1][r][lane];
      ob1[r] += cmb[qw][1][16 + r][lane];
    }
    lra += cmbl[qw][0][lane];
    lrb += cmbl[qw][1][lane];

    float rla = 1.f / lra, rlb = 1.f / lrb;
#pragma unroll
    for (int r = 0; r < 16; ++r) {
      int crow = (r & 3) + 8 * (r >> 2) + 4 * hi;
      float rva = __shfl(rla, crow, 64);
      float rvb = __shfl(rlb, crow, 64);
      size_t rowa = ((size_t)b * 2048 + qbase_a + crow) * 1024 + h * 64 + l31;
      size_t rowb = ((size_t)b * 2048 + qbase_b + crow) * 1024 + h * 64 + l31;
      ctx[rowa]      = f2bf(oa0[r] * rva);
      ctx[rowa + 32] = f2bf(oa1[r] * rva);
      ctx[rowb]      = f2bf(ob0[r] * rvb);
      ctx[rowb + 32] = f2bf(ob1[r] * rvb);
    }
  }
}

// ---------------- launch ----------------
extern "C" void kernel_launch(void* const* d_in, const int* in_sizes, int n_in,
                              void* d_out, int out_size, void* d_ws, size_t ws_size,
                              hipStream_t stream) {
  const float* q  = (const float*)d_in[0];
  const float* k  = (const float*)d_in[1];
  const float* v  = (const float*)d_in[2];
  const int* mask = (const int*)d_in[3];
  const float* Wq = (const float*)d_in[4];
  const float* Wk = (const float*)d_in[5];
  const float* Wv = (const float*)d_in[6];
  const float* Wo = (const float*)d_in[7];

  u16* ws = (u16*)d_ws;
  const size_t NX = (size_t)4096 * 1024;
  const size_t NW = (size_t)1024 * 1024;
  u16* Wqb = ws + 3 * NX;
  u16* Qh  = Wqb + 4 * NW;          // Qh | KP | VP consecutive
  u16* ctx = Qh + 3 * NX;
  u32* mpk = (u32*)ws;              // 1 MB

  cvt_w<<<dim3(1024, 4), 256, 0, stream>>>(Wq, Wk, Wv, Wo,
                                           Wqb, Wqb + NW, Wqb + 2 * NW, Wqb + 3 * NW);
  pack_mask<<<dim3(512), 256, 0, stream>>>(mask, mpk);
  gemm_qkv<<<dim3(32, 8, 3), 256, 0, stream>>>(q, k, v, Wqb, Qh);
  attn_kern<<<dim3(512), 256, 0, stream>>>(Qh, Qh + NX, Qh + 2 * NX, mpk, ctx);
  gemm_out<<<dim3(64, 8), 256, 0, stream>>>(ctx, Wqb + 3 * NW, (float*)d_out);
}